// Round 10
// baseline (302.869 us; speedup 1.0000x reference)
//
#include <hip/hip_runtime.h>
#include <hip/hip_bf16.h>

// Problem constants
#define B_  2
#define L_  512
#define D_  768
#define H_  12
#define E_  32
#define M_  4
#define P_  256
#define EMB_ 768
#define BS_ 64
#define C_  97
#define N_  (B_*P_)   // 512

#define KTOT_    49152      // EMB*BS
#define CPAD_    112        // 97 padded to 7*16
#define KSPLIT_  64
#define KCHUNK_  (KTOT_/KSPLIT_)   // 768, 12 ks-steps of 64

typedef __hip_bfloat16 bf16;
typedef __attribute__((ext_vector_type(8))) short bf16x8;
typedef __attribute__((ext_vector_type(4))) float f32x4;

__device__ inline float ldIn(const void* p, long idx, int isbf) {
    return isbf ? (float)((const bf16*)p)[idx] : ((const float*)p)[idx];
}

__device__ inline unsigned short f2bf(float f) {
    bf16 h = (bf16)f;
    return *(unsigned short*)&h;
}

// ---------------- K0: dtype detection + c23 zero-init ----------------
__global__ void dtype_detect(const void* __restrict__ seq, int* __restrict__ flag,
                             float* __restrict__ c23) {
    __shared__ int cnt;
    if (threadIdx.x == 0) cnt = 0;
    if (threadIdx.x < 2*C_) c23[threadIdx.x] = 0.f;
    __syncthreads();
    const unsigned short* u = (const unsigned short*)seq;
    int bad = 0;
    for (int i = threadIdx.x; i < 1024; i += 256) {
        unsigned short e = (u[i] >> 7) & 0xFF;
        if (e >= 140) bad++;
    }
    atomicAdd(&cnt, bad);
    __syncthreads();
    if (threadIdx.x == 0) flag[0] = (cnt < 16) ? 1 : 0;   // 1 = bf16 inputs
}

// ---------------- prep: z<8 transposes (32k x 64n), z=8 W_bil->f32, z=9 c23, z=10 W_rel conv ----
struct PrepArgs {
    const void* src[8];
    long off[8];
    int K[8];
    int Ncols[8];
    int Npad[8];
    unsigned short* dst[8];
    const void* W_bil;  float* W_bilF;
    const void* b_f; const void* W_unet; const void* b_unet;
    const void* W_mlp; const void* b_mlp; float* c23;
    const void* W_rel; unsigned short* WBt;
};

union PrepSm {
    float T[32][65];                 // 8320 B
    unsigned short TW[CPAD_][72];    // 16128 B
};

__global__ void prep_kernel(PrepArgs a, const int* __restrict__ dtf) {
    int isbf = dtf[0];
    int z = blockIdx.z;
    __shared__ PrepSm sm;
    int tid = threadIdx.x;
    if (z < 8) {
        int K = a.K[z], Ncols = a.Ncols[z], Npad = a.Npad[z];
        int k0 = blockIdx.x*32, n0 = blockIdx.y*64;
        if (k0 >= K || n0 >= Npad) return;
        const void* src = a.src[z];
        long off = a.off[z];
        unsigned short* dst = a.dst[z];
        int c64 = tid & 63, r4 = tid >> 6;
        for (int p = 0; p < 8; p++) {
            int r = r4 + p*4;
            int n = n0 + c64;
            sm.T[r][c64] = (n < Ncols) ? ldIn(src, off + (long)(k0+r)*Ncols + n, isbf) : 0.f;
        }
        __syncthreads();
        int cc = tid & 31, n8 = tid >> 5;
        for (int p = 0; p < 8; p++) {
            int nn = n8 + p*8;
            dst[(long)(n0+nn)*K + k0 + cc] = f2bf(sm.T[cc][nn]);
        }
    } else if (z == 8) {
        int lin = blockIdx.y*48 + blockIdx.x;
        int idx = lin*256 + tid;
        if (idx < 291*C_) a.W_bilF[idx] = ldIn(a.W_bil, idx, isbf);
    } else if (z == 9) {
        int lin = blockIdx.y*48 + blockIdx.x;
        if (lin >= 8) return;
        int c = tid;
        if (c >= C_) return;
        float s2 = 0.f, s3 = 0.f;
        int d0 = lin*96;
        for (int i = 0; i < 96; i++) {
            int d = d0 + i;
            float bf = ldIn(a.b_f, d, isbf);
            s2 += bf * ldIn(a.W_unet, (long)d*C_ + c, isbf);
            s3 += bf * ldIn(a.W_mlp,  (long)d*C_ + c, isbf);
        }
        if (lin == 0) {
            s2 += ldIn(a.b_unet, c, isbf);
            s3 += ldIn(a.b_mlp,  c, isbf);
        }
        atomicAdd(&a.c23[c], s2);
        atomicAdd(&a.c23[C_ + c], s3);
    } else {
        int lin = blockIdx.y*48 + blockIdx.x;
        if (lin >= KTOT_/64) return;
        int k0 = lin * 64;
        for (int idx = tid; idx < 64*97; idx += 256) {
            int kk = idx / 97, c = idx % 97;
            sm.TW[c][kk] = f2bf(ldIn(a.W_rel, (long)(k0+kk)*C_ + c, isbf));
        }
        for (int idx = tid; idx < 15*64; idx += 256) {
            sm.TW[97 + (idx>>6)][idx & 63] = 0;
        }
        __syncthreads();
        for (int t = 0; t < 4; t++) {
            int idx = tid + t*256;
            if (idx < 896) {
                int c = idx >> 3, kc = idx & 7;
                *(uint4*)(a.WBt + (long)c*KTOT_ + k0 + kc*8) = *(uint4*)&sm.TW[c][kc*8];
            }
        }
    }
}

// ---------------- gather: bx<768 entatt, else ment ----------------
__global__ void gather_kernel(const void* __restrict__ seq, const void* __restrict__ attn,
                              const int* __restrict__ entity_pos,
                              unsigned short* __restrict__ mentb, float* __restrict__ ent_emb,
                              float* __restrict__ ent_att, const int* __restrict__ dtf) {
    int isbf = dtf[0];
    if (blockIdx.x < 768) {
        int beh = blockIdx.x;
        int h = beh % H_;
        int be = beh / H_;
        int b = be >> 5;
        int pos[M_];
        for (int m = 0; m < M_; m++) pos[m] = entity_pos[be*M_+m] + 1;
        for (int l = threadIdx.x; l < L_; l += 256) {
            float s = 0.f;
            for (int m = 0; m < M_; m++)
                s += ldIn(attn, (((long)(b*H_ + h))*L_ + pos[m])*L_ + l, isbf);
            ent_att[(long)beh*L_ + l] = 0.25f * s;
        }
    } else {
        int be = blockIdx.x - 768;
        int b = be >> 5;
        int pos[M_];
        for (int m = 0; m < M_; m++) pos[m] = entity_pos[be*M_+m] + 1;
        for (int d = threadIdx.x; d < D_; d += 256) {
            float x[M_];
            for (int m = 0; m < M_; m++) {
                x[m] = ldIn(seq, ((long)b*L_ + pos[m])*D_ + d, isbf);
                mentb[((long)be*M_ + m)*D_ + d] = f2bf(x[m]);
            }
            float mx = fmaxf(fmaxf(x[0],x[1]), fmaxf(x[2],x[3]));
            float s = expf(x[0]-mx)+expf(x[1]-mx)+expf(x[2]-mx)+expf(x[3]-mx);
            ent_emb[(long)be*D_ + d] = mx + logf(s);
        }
    }
}

// ---------------- K3: ht_att (bf16) = normalize_L( mean_H(ha*ta) ) ----------------
__global__ void htatt_kernel(const float* __restrict__ ent_att, const int* __restrict__ hts,
                             unsigned short* __restrict__ htb) {
    int bp = blockIdx.x;
    int b = bp >> 8;
    int h_e = hts[bp*2+0], t_e = hts[bp*2+1];
    const float* ea_h = ent_att + (long)((b*E_ + h_e)*H_)*L_;
    const float* ea_t = ent_att + (long)((b*E_ + t_e)*H_)*L_;
    __shared__ float red[256];
    float v[2];
    for (int t = 0; t < 2; t++) {
        int l = threadIdx.x + t*256;
        float s = 0.f;
        for (int h = 0; h < H_; h++) s += ea_h[h*L_+l] * ea_t[h*L_+l];
        v[t] = s * (1.0f/H_);
    }
    red[threadIdx.x] = v[0] + v[1];
    __syncthreads();
    for (int off = 128; off > 0; off >>= 1) {
        if (threadIdx.x < off) red[threadIdx.x] += red[threadIdx.x+off];
        __syncthreads();
    }
    float inv = 1.0f / (red[0] + 1e-5f);
    for (int t = 0; t < 2; t++) {
        int l = threadIdx.x + t*256;
        htb[(long)bp*L_ + l] = f2bf(v[t] * inv);
    }
}

// ---------------- catb: hcatb=[hs,rs], tcatb=[ts,rs] in bf16 ----------------
__global__ void catb_kernel(const float* __restrict__ ent_emb, const float* __restrict__ rs,
                            const int* __restrict__ hts,
                            unsigned short* __restrict__ hcatb, unsigned short* __restrict__ tcatb) {
    int n = blockIdx.x;
    int b = n >> 8;
    int h_e = hts[n*2+0], t_e = hts[n*2+1];
    const float* eh = ent_emb + (long)(b*E_ + h_e)*D_;
    const float* et = ent_emb + (long)(b*E_ + t_e)*D_;
    const float* r  = rs + (long)n*D_;
    for (int k = threadIdx.x; k < D_; k += 256) {
        hcatb[(long)n*1536 + k] = f2bf(eh[k]);
        tcatb[(long)n*1536 + k] = f2bf(et[k]);
        unsigned short rb = f2bf(r[k]);
        hcatb[(long)n*1536 + 768 + k] = rb;
        tcatb[(long)n*1536 + 768 + k] = rb;
    }
}

// ---------------- Generic MFMA GEMM: barrier-free, direct per-lane fragment loads ----------------
struct MfmaJob {
    const unsigned short* A[4];
    const unsigned short* Bt[4];
    const void* bias[4];
    void* C[4];
    int K[4];
    int ldc[4];
    int act[4];
    int obf[4];
};

__global__ void mfma_nt2_kernel(MfmaJob args, const int* __restrict__ dtf) {
    int z = blockIdx.z;
    const unsigned short* A  = args.A[z];
    const unsigned short* Bt = args.Bt[z];
    const void* bias = args.bias[z];
    void* C = args.C[z];
    int K = args.K[z], ldc = args.ldc[z], act = args.act[z], obf = args.obf[z];
    int m0 = blockIdx.x*64, n0 = blockIdx.y*64;
    int tid = threadIdx.x, wave = tid>>6, lane = tid&63;
    int lm = lane&15, lq = lane>>4;
    const unsigned short* arow = A + (long)(m0 + wave*16 + lm)*K + lq*8;
    const unsigned short* brow0 = Bt + (long)(n0 +      lm)*K + lq*8;
    const unsigned short* brow1 = Bt + (long)(n0 + 16 + lm)*K + lq*8;
    const unsigned short* brow2 = Bt + (long)(n0 + 32 + lm)*K + lq*8;
    const unsigned short* brow3 = Bt + (long)(n0 + 48 + lm)*K + lq*8;
    f32x4 acc[4] = {};
    #pragma unroll 8
    for (int k0 = 0; k0 < K; k0 += 32) {
        bf16x8 af = *(const bf16x8*)(arow + k0);
        bf16x8 b0 = *(const bf16x8*)(brow0 + k0);
        bf16x8 b1 = *(const bf16x8*)(brow1 + k0);
        bf16x8 b2 = *(const bf16x8*)(brow2 + k0);
        bf16x8 b3 = *(const bf16x8*)(brow3 + k0);
        acc[0] = __builtin_amdgcn_mfma_f32_16x16x32_bf16(af, b0, acc[0], 0, 0, 0);
        acc[1] = __builtin_amdgcn_mfma_f32_16x16x32_bf16(af, b1, acc[1], 0, 0, 0);
        acc[2] = __builtin_amdgcn_mfma_f32_16x16x32_bf16(af, b2, acc[2], 0, 0, 0);
        acc[3] = __builtin_amdgcn_mfma_f32_16x16x32_bf16(af, b3, acc[3], 0, 0, 0);
    }
    int isbf = dtf[0];
    for (int ct = 0; ct < 4; ct++) {
        int n = n0 + ct*16 + lm;
        float bia = bias ? ldIn(bias, n, isbf) : 0.f;
        for (int r = 0; r < 4; r++) {
            int m = m0 + wave*16 + lq*4 + r;
            float v = acc[ct][r] + bia;
            if (act == 1) v = tanhf(v);
            if (obf) ((unsigned short*)C)[(long)m*ldc + n] = f2bf(v);
            else     ((float*)C)[(long)m*ldc + n] = v;
        }
    }
}

// ================= r1: barrier-free MFMA, on-the-fly A from registers, direct B =================
// grid (KSPLIT_, 8): kz fastest -> XCD slice affinity. partial layout: [n][kz][c]
__global__ void r1_mfma_kernel(const float* __restrict__ hz, const float* __restrict__ tz,
                               const unsigned short* __restrict__ WBt,
                               float* __restrict__ partial) {
    int kz = blockIdx.x;
    int n0 = blockIdx.y * 64;
    int kbase = kz * KCHUNK_;
    int gi0 = kbase >> 6;
    int g0 = kbase >> 12;
    int g1 = min(g0 + 1, EMB_/64 - 1);
    int tid = threadIdx.x;
    int wave = tid >> 6, lane = tid & 63;
    int lm = lane & 15, lq = lane >> 4;
    int myrow = n0 + wave*16 + lm;

    // per-lane register residency: hz[myrow][gi0..gi0+11], tz[myrow][{g0,g1}*64 + half*32 + lq*8 ..+7]
    float hzv[12];
    {
        const float* hp = hz + (long)myrow*EMB_ + gi0;
        float4 h0 = *(const float4*)(hp);
        float4 h1 = *(const float4*)(hp + 4);
        float4 h2 = *(const float4*)(hp + 8);
        hzv[0]=h0.x; hzv[1]=h0.y; hzv[2]=h0.z; hzv[3]=h0.w;
        hzv[4]=h1.x; hzv[5]=h1.y; hzv[6]=h1.z; hzv[7]=h1.w;
        hzv[8]=h2.x; hzv[9]=h2.y; hzv[10]=h2.z; hzv[11]=h2.w;
    }
    float tzc[2][2][8];   // [g][half][e]
    const float* tp = tz + (long)myrow*EMB_;
    for (int g = 0; g < 2; g++) {
        int gg = (g == 0) ? g0 : g1;
        for (int half = 0; half < 2; half++) {
            const float* p = tp + gg*64 + half*32 + lq*8;
            float4 v0 = *(const float4*)p;
            float4 v1 = *(const float4*)(p + 4);
            tzc[g][half][0]=v0.x; tzc[g][half][1]=v0.y; tzc[g][half][2]=v0.z; tzc[g][half][3]=v0.w;
            tzc[g][half][4]=v1.x; tzc[g][half][5]=v1.y; tzc[g][half][6]=v1.z; tzc[g][half][7]=v1.w;
        }
    }
    const unsigned short* wb = WBt + (long)lm*KTOT_ + kbase + lq*8;

    f32x4 acc[7] = {};
    #pragma unroll
    for (int ks = 0; ks < 12; ks++) {
        int sel = (((kbase + ks*64) >> 12) > g0) ? 1 : 0;
        float hv = hzv[ks];
        #pragma unroll
        for (int half = 0; half < 2; half++) {
            unsigned short o[8];
            #pragma unroll
            for (int e = 0; e < 8; e++) {
                float tv = sel ? tzc[1][half][e] : tzc[0][half][e];
                o[e] = f2bf(tv * hv);
            }
            bf16x8 afrag = *(bf16x8*)o;
            long koff = ks*64 + half*32;
            #pragma unroll
            for (int ct = 0; ct < 7; ct++) {
                bf16x8 bfrag = *(const bf16x8*)(wb + (long)ct*16*KTOT_ + koff);
                acc[ct] = __builtin_amdgcn_mfma_f32_16x16x32_bf16(afrag, bfrag, acc[ct], 0, 0, 0);
            }
        }
    }
    for (int ct = 0; ct < 7; ct++) {
        int c = ct*16 + lm;
        for (int r = 0; r < 4; r++) {
            int nl = wave*16 + lq*4 + r;
            partial[((long)(n0+nl)*KSPLIT_ + kz)*CPAD_ + c] = acc[ct][r];
        }
    }
}

// ---------------- fused: r1 streaming reduce + r2/r3 LSE + final projection ----------------
__global__ void r23out_kernel(const float* __restrict__ partial, const void* __restrict__ b_rel,
                              const float* __restrict__ mu, const float* __restrict__ c23,
                              const int* __restrict__ hts, const int* __restrict__ mention_idx,
                              const float* __restrict__ W_bilF, const void* __restrict__ b_bil,
                              void* __restrict__ out, const int* __restrict__ dtf) {
    int bp = blockIdx.x;
    int b = bp >> 8;
    int c = threadIdx.x;
    int isbf = dtf[0];
    __shared__ float row[292];
    if (c < C_) {
        const float* pr = partial + (long)bp*KSPLIT_*CPAD_;
        float r1v = 0.f;
        #pragma unroll 8
        for (int kz = 0; kz < KSPLIT_; kz++)
            r1v += pr[kz*CPAD_ + c];
        r1v += ldIn(b_rel, c, isbf);
        int h_e = hts[bp*2+0], t_e = hts[bp*2+1];
        const float* mu2h = mu;
        const float* mu2t = mu + 32768;
        const float* mu3h = mu + 65536;
        const float* mu3t = mu + 98304;
        float ah2[4], at2[4], ah3[4], at3[4];
        for (int m = 0; m < 4; m++) {
            int emh = mention_idx[(b*E_ + h_e)*M_ + m];
            int emt = mention_idx[(b*E_ + t_e)*M_ + m];
            ah2[m] = mu2h[(long)(b*128 + emh)*128 + c];
            ah3[m] = mu3h[(long)(b*128 + emh)*128 + c];
            at2[m] = mu2t[(long)(b*128 + emt)*128 + c];
            at3[m] = mu3t[(long)(b*128 + emt)*128 + c];
        }
        float c2 = c23[c], c3 = c23[C_ + c];
        float v2[16], v3[16];
        int q = 0;
        for (int i = 0; i < 4; i++) {
            for (int j = 0; j < 4; j++, q++) {
                float x2 = ah2[i] + at2[j] + c2;
                v2[q] = tanhf(x2);
                float x3 = ah3[i] + at3[j] + c3;
                float t = tanhf(0.7978845608028654f * (x3 + 0.044715f*x3*x3*x3));
                v3[q] = 0.5f * x3 * (1.0f + t);
            }
        }
        float m2 = v2[0], m3 = v3[0];
        for (q = 1; q < 16; q++) { m2 = fmaxf(m2, v2[q]); m3 = fmaxf(m3, v3[q]); }
        float s2 = 0.f, s3 = 0.f;
        for (q = 0; q < 16; q++) { s2 += expf(v2[q]-m2); s3 += expf(v3[q]-m3); }
        row[c]        = r1v;
        row[C_ + c]   = m2 + logf(s2);
        row[2*C_ + c] = m3 + logf(s3);
    }
    __syncthreads();
    if (c >= C_) return;
    float a0 = 0.f, a1 = 0.f, a2 = 0.f, a3 = 0.f;
    #pragma unroll 4
    for (int k = 0; k < 288; k += 4) {
        a0 += row[k+0] * W_bilF[(k+0)*C_ + c];
        a1 += row[k+1] * W_bilF[(k+1)*C_ + c];
        a2 += row[k+2] * W_bilF[(k+2)*C_ + c];
        a3 += row[k+3] * W_bilF[(k+3)*C_ + c];
    }
    a0 += row[288] * W_bilF[288*C_ + c];
    a1 += row[289] * W_bilF[289*C_ + c];
    a2 += row[290] * W_bilF[290*C_ + c];
    float v = a0 + a1 + a2 + a3 + ldIn(b_bil, c, isbf);
    if (isbf) ((bf16*)out)[(long)bp*C_ + c] = (bf16)v;
    else      ((float*)out)[(long)bp*C_ + c] = v;
}

extern "C" void kernel_launch(void* const* d_in, const int* in_sizes, int n_in,
                              void* d_out, int out_size, void* d_ws, size_t ws_size,
                              hipStream_t stream) {
    const void* seq        = d_in[0];
    const void* attn       = d_in[1];
    const int*  entity_pos = (const int*)d_in[2];
    const int*  hts        = (const int*)d_in[3];
    const int*  mention_idx= (const int*)d_in[4];
    const void* W_head     = d_in[5];
    const void* b_head     = d_in[6];
    const void* W_tail     = d_in[7];
    const void* b_tail     = d_in[8];
    const void* W_rel      = d_in[9];
    const void* b_rel      = d_in[10];
    const void* W_fh       = d_in[11];
    const void* W_ft       = d_in[12];
    const void* b_f        = d_in[13];
    const void* W_unet     = d_in[14];
    const void* b_unet     = d_in[15];
    const void* W_mlp      = d_in[16];
    const void* b_mlp      = d_in[17];
    const void* W_bil      = d_in[18];
    const void* b_bil      = d_in[19];

    float* w = (float*)d_ws;
    int*   dtf      = (int*)w;                               // 64
    unsigned short* mentb = (unsigned short*)(w + 64);       // 98304 fl
    float* ent_emb  = w + 98368;                             // 49152
    float* ent_att  = w + 147520;                            // 393216
    unsigned short* htb = (unsigned short*)(w + 540736);     // 131072 fl
    float* rs       = w + 671808;                            // 393216
    float* hz       = w + 1065024;                           // 393216
    float* tz       = w + 1458240;                           // 393216
    float* mu       = w + 1851456;                           // 131072
    float* c23      = w + 1982528;                           // 256
    unsigned short* seqT  = (unsigned short*)(w + 1982784);  // 393216 fl
    unsigned short* WhT   = (unsigned short*)(w + 2376000);  // 589824 fl
    unsigned short* WtT   = (unsigned short*)(w + 2965824);  // 589824 fl
    unsigned short* WfhT  = (unsigned short*)(w + 3555648);  // 294912 fl
    unsigned short* WftT  = (unsigned short*)(w + 3850560);  // 294912 fl
    unsigned short* WunetT= (unsigned short*)(w + 4145472);  // 49152 fl
    unsigned short* WmlpT = (unsigned short*)(w + 4194624);  // 49152 fl
    unsigned short* Tbh   = (unsigned short*)(w + 4243776);  // 98304 fl
    unsigned short* Tbt   = (unsigned short*)(w + 4342080);  // 98304 fl
    unsigned short* hcatb = (unsigned short*)(w + 4440384);  // 393216 fl
    unsigned short* tcatb = (unsigned short*)(w + 4833600);  // 393216 fl
    unsigned short* WBt   = (unsigned short*)(w + 5226816);  // 2752512 fl
    float* partial  = w + 7979328;                           // 3670016 fl
    float* W_bilF   = w + 11649344;                          // 28227 fl

    // 0. dtype detection + c23 init
    dtype_detect<<<1, 256, 0, stream>>>(seq, dtf, c23);
    // 1. prep
    {
        PrepArgs a = {};
        const void* srcs[8] = {W_head, W_tail, W_fh, W_ft, W_unet, W_mlp, seq, seq};
        long offs[8]   = {0,0,0,0,0,0,0,393216};
        int Ks[8]      = {1536,1536,768,768,768,768,512,512};
        int Ncols8[8]  = {768,768,768,768,97,97,768,768};
        int Npads[8]   = {768,768,768,768,128,128,768,768};
        unsigned short* dsts[8] = {WhT, WtT, WfhT, WftT, WunetT, WmlpT, seqT, seqT+393216};
        for (int z = 0; z < 8; z++) {
            a.src[z]=srcs[z]; a.off[z]=offs[z]; a.K[z]=Ks[z];
            a.Ncols[z]=Ncols8[z]; a.Npad[z]=Npads[z]; a.dst[z]=dsts[z];
        }
        a.W_bil = W_bil; a.W_bilF = W_bilF;
        a.b_f = b_f; a.W_unet = W_unet; a.b_unet = b_unet;
        a.W_mlp = W_mlp; a.b_mlp = b_mlp; a.c23 = c23;
        a.W_rel = W_rel; a.WBt = WBt;
        prep_kernel<<<dim3(48, 16, 11), 256, 0, stream>>>(a, dtf);
    }
    // 2. gather: entatt + ment
    gather_kernel<<<768 + 64, 256, 0, stream>>>(seq, attn, entity_pos, mentb, ent_emb, ent_att, dtf);
    // 3. ht attention (normalized, bf16)
    htatt_kernel<<<N_, 256, 0, stream>>>(ent_att, hts, htb);
    // 4. gemmA: rs (z=0,1) + T_{h,t} (z=2,3)
    {
        MfmaJob ga = {};
        for (int z = 0; z < 2; z++) {
            ga.A[z] = htb + (long)z*256*512; ga.Bt[z] = seqT + (long)z*393216;
            ga.bias[z] = nullptr; ga.C[z] = rs + (long)z*256*768;
            ga.K[z] = 512; ga.ldc[z] = 768; ga.act[z] = 0; ga.obf[z] = 0;
        }
        ga.A[2] = mentb; ga.Bt[2] = WfhT; ga.bias[2] = nullptr; ga.C[2] = Tbh;
        ga.K[2] = 768; ga.ldc[2] = 768; ga.act[2] = 0; ga.obf[2] = 1;
        ga.A[3] = mentb; ga.Bt[3] = WftT; ga.bias[3] = nullptr; ga.C[3] = Tbt;
        ga.K[3] = 768; ga.ldc[3] = 768; ga.act[3] = 0; ga.obf[3] = 1;
        mfma_nt2_kernel<<<dim3(4, 12, 4), 256, 0, stream>>>(ga, dtf);
    }
    // 5. concatenated inputs (bf16)
    catb_kernel<<<N_, 256, 0, stream>>>(ent_emb, rs, hts, hcatb, tcatb);
    // 6. gemmB: hz/tz = tanh(cat @ W + b)
    {
        MfmaJob ga = {};
        ga.A[0] = hcatb; ga.Bt[0] = WhT; ga.bias[0] = b_head; ga.C[0] = hz;
        ga.A[1] = tcatb; ga.Bt[1] = WtT; ga.bias[1] = b_tail; ga.C[1] = tz;
        for (int z = 0; z < 2; z++) { ga.K[z] = 1536; ga.ldc[z] = 768; ga.act[z] = 1; ga.obf[z] = 0; }
        mfma_nt2_kernel<<<dim3(8, 12, 2), 256, 0, stream>>>(ga, dtf);
    }
    // 7. gemmC: mu_q = T @ W_{unet,mlp}
    {
        MfmaJob ga = {};
        const unsigned short* As[4] = {Tbh, Tbt, Tbh, Tbt};
        const unsigned short* Bs[4] = {WunetT, WunetT, WmlpT, WmlpT};
        for (int q = 0; q < 4; q++) {
            ga.A[q] = As[q]; ga.Bt[q] = Bs[q]; ga.bias[q] = nullptr;
            ga.C[q] = mu + q*32768;
            ga.K[q] = 768; ga.ldc[q] = 128; ga.act[q] = 0; ga.obf[q] = 0;
        }
        mfma_nt2_kernel<<<dim3(4, 2, 4), 256, 0, stream>>>(ga, dtf);
    }
    // 8. r1 partials (barrier-free MFMA, kz-fastest grid)
    r1_mfma_kernel<<<dim3(KSPLIT_, 8), 256, 0, stream>>>(hz, tz, WBt, partial);
    // 9. fused reduce + r2/r3 + final projection
    r23out_kernel<<<N_, 128, 0, stream>>>(partial, b_rel, mu, c23, hts, mention_idx,
                                          W_bilF, b_bil, d_out, dtf);
}

// Round 11
// 272.565 us; speedup vs baseline: 1.1112x; 1.1112x over previous
//
#include <hip/hip_runtime.h>
#include <hip/hip_bf16.h>

// Problem constants
#define B_  2
#define L_  512
#define D_  768
#define H_  12
#define E_  32
#define M_  4
#define P_  256
#define EMB_ 768
#define BS_ 64
#define C_  97
#define N_  (B_*P_)   // 512

#define KTOT_    49152      // EMB*BS
#define CPAD_    112        // 97 padded to 7*16
#define KSPLIT_  64
#define KCHUNK_  (KTOT_/KSPLIT_)   // 768, 12 ks-steps of 64

typedef __hip_bfloat16 bf16;
typedef __attribute__((ext_vector_type(8))) short bf16x8;
typedef __attribute__((ext_vector_type(4))) float f32x4;

__device__ inline float ldIn(const void* p, long idx, int isbf) {
    return isbf ? (float)((const bf16*)p)[idx] : ((const float*)p)[idx];
}

__device__ inline unsigned short f2bf(float f) {
    bf16 h = (bf16)f;
    return *(unsigned short*)&h;
}

__device__ inline float bf2f(unsigned short u) {
    bf16 h = *(bf16*)&u;
    return (float)h;
}

// ---------------- K0: dtype detection + c23 zero-init ----------------
__global__ void dtype_detect(const void* __restrict__ seq, int* __restrict__ flag,
                             float* __restrict__ c23) {
    __shared__ int cnt;
    if (threadIdx.x == 0) cnt = 0;
    if (threadIdx.x < 2*C_) c23[threadIdx.x] = 0.f;
    __syncthreads();
    const unsigned short* u = (const unsigned short*)seq;
    int bad = 0;
    for (int i = threadIdx.x; i < 1024; i += 256) {
        unsigned short e = (u[i] >> 7) & 0xFF;
        if (e >= 140) bad++;
    }
    atomicAdd(&cnt, bad);
    __syncthreads();
    if (threadIdx.x == 0) flag[0] = (cnt < 16) ? 1 : 0;   // 1 = bf16 inputs
}

// ---- prep: z<8 transposes, z=8 W_bil->f32, z=9 c23, z=10 W_rel conv, z=11 entatt, z=12 ment ----
struct PrepArgs {
    const void* src[8];
    long off[8];
    int K[8];
    int Ncols[8];
    int Npad[8];
    unsigned short* dst[8];
    const void* W_bil;  float* W_bilF;
    const void* b_f; const void* W_unet; const void* b_unet;
    const void* W_mlp; const void* b_mlp; float* c23;
    const void* W_rel; unsigned short* WBt;
    const void* seq; const void* attn; const int* entity_pos;
    unsigned short* mentb; float* ent_emb; float* ent_att;
};

union PrepSm {
    float T[32][65];                 // 8320 B
    unsigned short TW[CPAD_][72];    // 16128 B
};

__global__ void prep_kernel(PrepArgs a, const int* __restrict__ dtf) {
    int isbf = dtf[0];
    int z = blockIdx.z;
    __shared__ PrepSm sm;
    int tid = threadIdx.x;
    int lin = blockIdx.y*48 + blockIdx.x;
    if (z < 8) {
        int K = a.K[z], Ncols = a.Ncols[z], Npad = a.Npad[z];
        int k0 = blockIdx.x*32, n0 = blockIdx.y*64;
        if (k0 >= K || n0 >= Npad) return;
        const void* src = a.src[z];
        long off = a.off[z];
        unsigned short* dst = a.dst[z];
        int c64 = tid & 63, r4 = tid >> 6;
        for (int p = 0; p < 8; p++) {
            int r = r4 + p*4;
            int n = n0 + c64;
            sm.T[r][c64] = (n < Ncols) ? ldIn(src, off + (long)(k0+r)*Ncols + n, isbf) : 0.f;
        }
        __syncthreads();
        int cc = tid & 31, n8 = tid >> 5;
        for (int p = 0; p < 8; p++) {
            int nn = n8 + p*8;
            dst[(long)(n0+nn)*K + k0 + cc] = f2bf(sm.T[cc][nn]);
        }
    } else if (z == 8) {
        int idx = lin*256 + tid;
        if (idx < 291*C_) a.W_bilF[idx] = ldIn(a.W_bil, idx, isbf);
    } else if (z == 9) {
        if (lin >= 8) return;
        int c = tid;
        if (c >= C_) return;
        float s2 = 0.f, s3 = 0.f;
        int d0 = lin*96;
        for (int i = 0; i < 96; i++) {
            int d = d0 + i;
            float bf = ldIn(a.b_f, d, isbf);
            s2 += bf * ldIn(a.W_unet, (long)d*C_ + c, isbf);
            s3 += bf * ldIn(a.W_mlp,  (long)d*C_ + c, isbf);
        }
        if (lin == 0) {
            s2 += ldIn(a.b_unet, c, isbf);
            s3 += ldIn(a.b_mlp,  c, isbf);
        }
        atomicAdd(&a.c23[c], s2);
        atomicAdd(&a.c23[C_ + c], s3);
    } else if (z == 10) {
        if (lin >= KTOT_/64) return;
        int k0 = lin * 64;
        for (int idx = tid; idx < 64*97; idx += 256) {
            int kk = idx / 97, c = idx % 97;
            sm.TW[c][kk] = f2bf(ldIn(a.W_rel, (long)(k0+kk)*C_ + c, isbf));
        }
        for (int idx = tid; idx < 15*64; idx += 256) {
            sm.TW[97 + (idx>>6)][idx & 63] = 0;
        }
        __syncthreads();
        for (int t = 0; t < 4; t++) {
            int idx = tid + t*256;
            if (idx < 896) {
                int c = idx >> 3, kc = idx & 7;
                *(uint4*)(a.WBt + (long)c*KTOT_ + k0 + kc*8) = *(uint4*)&sm.TW[c][kc*8];
            }
        }
    } else if (z == 11) {
        // entatt: 768 blocks
        int beh = lin;
        int h = beh % H_;
        int be = beh / H_;
        int b = be >> 5;
        int pos[M_];
        for (int m = 0; m < M_; m++) pos[m] = a.entity_pos[be*M_+m] + 1;
        for (int l = tid; l < L_; l += 256) {
            float s = 0.f;
            for (int m = 0; m < M_; m++)
                s += ldIn(a.attn, (((long)(b*H_ + h))*L_ + pos[m])*L_ + l, isbf);
            a.ent_att[(long)beh*L_ + l] = 0.25f * s;
        }
    } else {
        // ment: 64 blocks
        if (lin >= B_*E_) return;
        int be = lin;
        int b = be >> 5;
        int pos[M_];
        for (int m = 0; m < M_; m++) pos[m] = a.entity_pos[be*M_+m] + 1;
        for (int d = tid; d < D_; d += 256) {
            float x[M_];
            for (int m = 0; m < M_; m++) {
                x[m] = ldIn(a.seq, ((long)b*L_ + pos[m])*D_ + d, isbf);
                a.mentb[((long)be*M_ + m)*D_ + d] = f2bf(x[m]);
            }
            float mx = fmaxf(fmaxf(x[0],x[1]), fmaxf(x[2],x[3]));
            float s = expf(x[0]-mx)+expf(x[1]-mx)+expf(x[2]-mx)+expf(x[3]-mx);
            a.ent_emb[(long)be*D_ + d] = mx + logf(s);
        }
    }
}

// ---------------- K3: ht_att (bf16) = normalize_L( mean_H(ha*ta) ) ----------------
__global__ void htatt_kernel(const float* __restrict__ ent_att, const int* __restrict__ hts,
                             unsigned short* __restrict__ htb) {
    int bp = blockIdx.x;
    int b = bp >> 8;
    int h_e = hts[bp*2+0], t_e = hts[bp*2+1];
    const float* ea_h = ent_att + (long)((b*E_ + h_e)*H_)*L_;
    const float* ea_t = ent_att + (long)((b*E_ + t_e)*H_)*L_;
    __shared__ float red[256];
    float v[2];
    for (int t = 0; t < 2; t++) {
        int l = threadIdx.x + t*256;
        float s = 0.f;
        for (int h = 0; h < H_; h++) s += ea_h[h*L_+l] * ea_t[h*L_+l];
        v[t] = s * (1.0f/H_);
    }
    red[threadIdx.x] = v[0] + v[1];
    __syncthreads();
    for (int off = 128; off > 0; off >>= 1) {
        if (threadIdx.x < off) red[threadIdx.x] += red[threadIdx.x+off];
        __syncthreads();
    }
    float inv = 1.0f / (red[0] + 1e-5f);
    for (int t = 0; t < 2; t++) {
        int l = threadIdx.x + t*256;
        htb[(long)bp*L_ + l] = f2bf(v[t] * inv);
    }
}

// ---------------- Generic MFMA GEMM (LDS double-buffered), gather-cat A option ----------------
struct MfmaJob {
    const unsigned short* A[6];
    const unsigned short* Bt[6];
    const void* bias[6];
    void* C[6];
    int K[6];
    int ldc[6];
    int act[6];
    int obf[6];
    int asrc[6];    // 1 -> A is gather-cat [ent_emb|rs] f32
    int aside[6];   // 0=h, 1=t
    int mx[6], my[6];
    const float* ent_emb;
    const float* rs;
    const int* hts;
};

__device__ inline uint4 loadAfrag(const unsigned short* A, const float* ent_emb,
                                  const float* rs, const int* hts,
                                  int asrc, int aside, int row, int K, int kcol) {
    if (!asrc) return *(const uint4*)(A + (long)row*K + kcol);
    const float* src;
    if (kcol < D_) {
        int b = row >> 8;
        int e = hts[row*2 + aside];
        src = ent_emb + ((long)(b*E_ + e))*D_ + kcol;
    } else {
        src = rs + (long)row*D_ + (kcol - D_);
    }
    float4 v0 = *(const float4*)src;
    float4 v1 = *(const float4*)(src + 4);
    unsigned short o[8] = {f2bf(v0.x),f2bf(v0.y),f2bf(v0.z),f2bf(v0.w),
                           f2bf(v1.x),f2bf(v1.y),f2bf(v1.z),f2bf(v1.w)};
    return *(uint4*)o;
}

__global__ void mfma_nt2_kernel(MfmaJob jb, const int* __restrict__ dtf) {
    int z = blockIdx.z;
    if ((int)blockIdx.x >= jb.mx[z] || (int)blockIdx.y >= jb.my[z]) return;
    const unsigned short* A  = jb.A[z];
    const unsigned short* Bt = jb.Bt[z];
    const void* bias = jb.bias[z];
    void* C = jb.C[z];
    int K = jb.K[z], ldc = jb.ldc[z], act = jb.act[z], obf = jb.obf[z];
    int asrc = jb.asrc[z], aside = jb.aside[z];
    __shared__ unsigned short Al[2][64][72];
    __shared__ unsigned short Btl[2][64][72];
    int m0 = blockIdx.x*64, n0 = blockIdx.y*64;
    int tid = threadIdx.x, wave = tid>>6, lane = tid&63;
    int lm = lane&15, lq = lane>>4;
    int rr = tid >> 3;                // 0..31
    int kc = (tid & 7) * 8;           // col offset in ushorts
    uint4 ra0, ra1, rb0, rb1;

    ra0 = loadAfrag(A, jb.ent_emb, jb.rs, jb.hts, asrc, aside, m0+rr, K, kc);
    ra1 = loadAfrag(A, jb.ent_emb, jb.rs, jb.hts, asrc, aside, m0+32+rr, K, kc);
    rb0 = *(const uint4*)(Bt + (long)(n0+rr)*K + kc);
    rb1 = *(const uint4*)(Bt + (long)(n0+32+rr)*K + kc);
    *(uint4*)&Al[0][rr][kc]     = ra0;
    *(uint4*)&Al[0][32+rr][kc]  = ra1;
    *(uint4*)&Btl[0][rr][kc]    = rb0;
    *(uint4*)&Btl[0][32+rr][kc] = rb1;

    int nst = K >> 6;
    f32x4 acc[4] = {};
    for (int ks = 0; ks < nst; ks++) {
        __syncthreads();
        if (ks+1 < nst) {
            int k0 = (ks+1) << 6;
            ra0 = loadAfrag(A, jb.ent_emb, jb.rs, jb.hts, asrc, aside, m0+rr, K, k0+kc);
            ra1 = loadAfrag(A, jb.ent_emb, jb.rs, jb.hts, asrc, aside, m0+32+rr, K, k0+kc);
            rb0 = *(const uint4*)(Bt + (long)(n0+rr)*K + k0 + kc);
            rb1 = *(const uint4*)(Bt + (long)(n0+32+rr)*K + k0 + kc);
        }
        int cb = ks & 1;
        for (int half = 0; half < 2; half++) {
            bf16x8 af = *(bf16x8*)&Al[cb][wave*16+lm][half*32+lq*8];
            #pragma unroll
            for (int ct = 0; ct < 4; ct++) {
                bf16x8 bfr = *(bf16x8*)&Btl[cb][ct*16+lm][half*32+lq*8];
                acc[ct] = __builtin_amdgcn_mfma_f32_16x16x32_bf16(af, bfr, acc[ct], 0, 0, 0);
            }
        }
        if (ks+1 < nst) {
            int nb = (ks+1) & 1;
            *(uint4*)&Al[nb][rr][kc]     = ra0;
            *(uint4*)&Al[nb][32+rr][kc]  = ra1;
            *(uint4*)&Btl[nb][rr][kc]    = rb0;
            *(uint4*)&Btl[nb][32+rr][kc] = rb1;
        }
    }
    int isbf = dtf[0];
    for (int ct = 0; ct < 4; ct++) {
        int n = n0 + ct*16 + lm;
        float bia = bias ? ldIn(bias, n, isbf) : 0.f;
        for (int r = 0; r < 4; r++) {
            int m = m0 + wave*16 + lq*4 + r;
            float v = acc[ct][r] + bia;
            if (act == 1) v = tanhf(v);
            if (obf) ((unsigned short*)C)[(long)m*ldc + n] = f2bf(v);
            else     ((float*)C)[(long)m*ldc + n] = v;
        }
    }
}

// ================= r1 via MFMA, on-the-fly A, double-buffered B, bf16 partial =================
// grid (KSPLIT_, 8): kz fastest -> XCD slice affinity. partial layout: [n][kz][c] bf16
__global__ void r1_mfma_kernel(const float* __restrict__ hz, const float* __restrict__ tz,
                               const unsigned short* __restrict__ WBt,
                               unsigned short* __restrict__ partial) {
    __shared__ float hzL[64][13];
    __shared__ unsigned short tzbL[64][136];
    __shared__ unsigned short Btl[2][CPAD_][72];
    int kz = blockIdx.x;
    int n0 = blockIdx.y * 64;
    int kbase = kz * KCHUNK_;
    int gi0 = kbase >> 6;
    int g0 = kbase >> 12;
    int g1 = min(g0 + 1, EMB_/64 - 1);
    int tid = threadIdx.x;
    int wave = tid >> 6, lane = tid & 63;
    int lm = lane & 15, lq = lane >> 4;

    for (int t = 0; t < 4; t++) {
        int id = tid + t*256;
        int n = id >> 4, q = id & 15;
        if (q < 12) hzL[n][q] = hz[(long)(n0+n)*EMB_ + gi0 + q];
    }
    for (int t = 0; t < 8; t++) {
        int id = tid + t*256;
        int n = id >> 5, c4 = (id & 31) * 4;
        int gcol = (c4 < 64) ? (g0*64 + c4) : (g1*64 + c4 - 64);
        float4 v = *(const float4*)(tz + (long)(n0+n)*EMB_ + gcol);
        unsigned short o[4] = {f2bf(v.x), f2bf(v.y), f2bf(v.z), f2bf(v.w)};
        *(uint2*)&tzbL[n][c4] = *(uint2*)o;
    }
    uint4 rb[4];
    #pragma unroll
    for (int t = 0; t < 4; t++) {
        int idx = tid + t*256;
        if (idx < 896) {
            int c = idx >> 3, k8 = (idx & 7)*8;
            rb[t] = *(const uint4*)(WBt + (long)c*KTOT_ + kbase + k8);
        }
    }
    #pragma unroll
    for (int t = 0; t < 4; t++) {
        int idx = tid + t*256;
        if (idx < 896) {
            int c = idx >> 3, k8 = (idx & 7)*8;
            *(uint4*)&Btl[0][c][k8] = rb[t];
        }
    }

    f32x4 acc[7] = {};
    for (int ks = 0; ks < KCHUNK_/64; ks++) {
        __syncthreads();
        if (ks+1 < KCHUNK_/64) {
            int k0 = kbase + (ks+1)*64;
            #pragma unroll
            for (int t = 0; t < 4; t++) {
                int idx = tid + t*256;
                if (idx < 896) {
                    int c = idx >> 3, k8 = (idx & 7)*8;
                    rb[t] = *(const uint4*)(WBt + (long)c*KTOT_ + k0 + k8);
                }
            }
        }
        int cb = ks & 1;
        int k0 = kbase + ks*64;
        int gsel = ((k0 >> 12) > g0) ? 64 : 0;
        float hv = hzL[wave*16 + lm][ks];
        for (int half = 0; half < 2; half++) {
            bf16x8 tzf = *(bf16x8*)&tzbL[wave*16 + lm][gsel + half*32 + lq*8];
            unsigned short o[8];
            #pragma unroll
            for (int e = 0; e < 8; e++)
                o[e] = f2bf(bf2f(((unsigned short*)&tzf)[e]) * hv);
            bf16x8 afrag = *(bf16x8*)o;
            #pragma unroll
            for (int ct = 0; ct < 7; ct++) {
                bf16x8 bfrag = *(bf16x8*)&Btl[cb][ct*16 + lm][half*32 + lq*8];
                acc[ct] = __builtin_amdgcn_mfma_f32_16x16x32_bf16(afrag, bfrag, acc[ct], 0, 0, 0);
            }
        }
        if (ks+1 < KCHUNK_/64) {
            int nb = (ks+1) & 1;
            #pragma unroll
            for (int t = 0; t < 4; t++) {
                int idx = tid + t*256;
                if (idx < 896) {
                    int c = idx >> 3, k8 = (idx & 7)*8;
                    *(uint4*)&Btl[nb][c][k8] = rb[t];
                }
            }
        }
    }
    for (int ct = 0; ct < 7; ct++) {
        int c = ct*16 + lm;
        for (int r = 0; r < 4; r++) {
            int nl = wave*16 + lq*4 + r;
            partial[((long)(n0+nl)*KSPLIT_ + kz)*CPAD_ + c] = f2bf(acc[ct][r]);
        }
    }
}

// ---------------- fused: r1 streaming reduce (bf16 partial) + r2/r3 LSE + final projection ----
__global__ void r23out_kernel(const unsigned short* __restrict__ partial, const void* __restrict__ b_rel,
                              const float* __restrict__ mu, const float* __restrict__ c23,
                              const int* __restrict__ hts, const int* __restrict__ mention_idx,
                              const float* __restrict__ W_bilF, const void* __restrict__ b_bil,
                              void* __restrict__ out, const int* __restrict__ dtf) {
    int bp = blockIdx.x;
    int b = bp >> 8;
    int c = threadIdx.x;
    int isbf = dtf[0];
    __shared__ float row[292];
    if (c < C_) {
        const unsigned short* pr = partial + (long)bp*KSPLIT_*CPAD_ + c;
        float r1v = 0.f;
        #pragma unroll 8
        for (int kz = 0; kz < KSPLIT_; kz++)
            r1v += bf2f(pr[kz*CPAD_]);
        r1v += ldIn(b_rel, c, isbf);
        int h_e = hts[bp*2+0], t_e = hts[bp*2+1];
        const float* mu2h = mu;
        const float* mu2t = mu + 32768;
        const float* mu3h = mu + 65536;
        const float* mu3t = mu + 98304;
        float ah2[4], at2[4], ah3[4], at3[4];
        for (int m = 0; m < 4; m++) {
            int emh = mention_idx[(b*E_ + h_e)*M_ + m];
            int emt = mention_idx[(b*E_ + t_e)*M_ + m];
            ah2[m] = mu2h[(long)(b*128 + emh)*128 + c];
            ah3[m] = mu3h[(long)(b*128 + emh)*128 + c];
            at2[m] = mu2t[(long)(b*128 + emt)*128 + c];
            at3[m] = mu3t[(long)(b*128 + emt)*128 + c];
        }
        float c2 = c23[c], c3 = c23[C_ + c];
        float v2[16], v3[16];
        int q = 0;
        for (int i = 0; i < 4; i++) {
            for (int j = 0; j < 4; j++, q++) {
                float x2 = ah2[i] + at2[j] + c2;
                v2[q] = tanhf(x2);
                float x3 = ah3[i] + at3[j] + c3;
                float t = tanhf(0.7978845608028654f * (x3 + 0.044715f*x3*x3*x3));
                v3[q] = 0.5f * x3 * (1.0f + t);
            }
        }
        float m2 = v2[0], m3 = v3[0];
        for (q = 1; q < 16; q++) { m2 = fmaxf(m2, v2[q]); m3 = fmaxf(m3, v3[q]); }
        float s2 = 0.f, s3 = 0.f;
        for (q = 0; q < 16; q++) { s2 += expf(v2[q]-m2); s3 += expf(v3[q]-m3); }
        row[c]        = r1v;
        row[C_ + c]   = m2 + logf(s2);
        row[2*C_ + c] = m3 + logf(s3);
    }
    __syncthreads();
    if (c >= C_) return;
    float a0 = 0.f, a1 = 0.f, a2 = 0.f, a3 = 0.f;
    #pragma unroll 4
    for (int k = 0; k < 288; k += 4) {
        a0 += row[k+0] * W_bilF[(k+0)*C_ + c];
        a1 += row[k+1] * W_bilF[(k+1)*C_ + c];
        a2 += row[k+2] * W_bilF[(k+2)*C_ + c];
        a3 += row[k+3] * W_bilF[(k+3)*C_ + c];
    }
    a0 += row[288] * W_bilF[288*C_ + c];
    a1 += row[289] * W_bilF[289*C_ + c];
    a2 += row[290] * W_bilF[290*C_ + c];
    float v = a0 + a1 + a2 + a3 + ldIn(b_bil, c, isbf);
    if (isbf) ((bf16*)out)[(long)bp*C_ + c] = (bf16)v;
    else      ((float*)out)[(long)bp*C_ + c] = v;
}

extern "C" void kernel_launch(void* const* d_in, const int* in_sizes, int n_in,
                              void* d_out, int out_size, void* d_ws, size_t ws_size,
                              hipStream_t stream) {
    const void* seq        = d_in[0];
    const void* attn       = d_in[1];
    const int*  entity_pos = (const int*)d_in[2];
    const int*  hts        = (const int*)d_in[3];
    const int*  mention_idx= (const int*)d_in[4];
    const void* W_head     = d_in[5];
    const void* b_head     = d_in[6];
    const void* W_tail     = d_in[7];
    const void* b_tail     = d_in[8];
    const void* W_rel      = d_in[9];
    const void* b_rel      = d_in[10];
    const void* W_fh       = d_in[11];
    const void* W_ft       = d_in[12];
    const void* b_f        = d_in[13];
    const void* W_unet     = d_in[14];
    const void* b_unet     = d_in[15];
    const void* W_mlp      = d_in[16];
    const void* b_mlp      = d_in[17];
    const void* W_bil      = d_in[18];
    const void* b_bil      = d_in[19];

    float* w = (float*)d_ws;
    int*   dtf      = (int*)w;                               // 64
    unsigned short* mentb = (unsigned short*)(w + 64);       // 98304 fl
    float* ent_emb  = w + 98368;                             // 49152
    float* ent_att  = w + 147520;                            // 393216
    unsigned short* htb = (unsigned short*)(w + 540736);     // 131072 fl
    float* rs       = w + 671808;                            // 393216
    float* hz       = w + 1065024;                           // 393216
    float* tz       = w + 1458240;                           // 393216
    float* mu       = w + 1851456;                           // 131072
    float* c23      = w + 1982528;                           // 256
    unsigned short* seqT  = (unsigned short*)(w + 1982784);  // 393216 fl
    unsigned short* WhT   = (unsigned short*)(w + 2376000);  // 589824 fl
    unsigned short* WtT   = (unsigned short*)(w + 2965824);  // 589824 fl
    unsigned short* WfhT  = (unsigned short*)(w + 3555648);  // 294912 fl
    unsigned short* WftT  = (unsigned short*)(w + 3850560);  // 294912 fl
    unsigned short* WunetT= (unsigned short*)(w + 4145472);  // 49152 fl
    unsigned short* WmlpT = (unsigned short*)(w + 4194624);  // 49152 fl
    unsigned short* Tbh   = (unsigned short*)(w + 4243776);  // 98304 fl
    unsigned short* Tbt   = (unsigned short*)(w + 4342080);  // 98304 fl
    unsigned short* WBt   = (unsigned short*)(w + 4440384);  // 2752512 fl
    unsigned short* partial = (unsigned short*)(w + 7192896);// 512*64*112 bf16 = 1835008 fl
    float* W_bilF   = w + 9027904;                           // 28227 fl

    // 0. dtype detection + c23 init
    dtype_detect<<<1, 256, 0, stream>>>(seq, dtf, c23);
    // 1. prep: transposes + W_bilF + c23 + W_rel conv + entatt + ment
    {
        PrepArgs a = {};
        const void* srcs[8] = {W_head, W_tail, W_fh, W_ft, W_unet, W_mlp, seq, seq};
        long offs[8]   = {0,0,0,0,0,0,0,393216};
        int Ks[8]      = {1536,1536,768,768,768,768,512,512};
        int Ncols8[8]  = {768,768,768,768,97,97,768,768};
        int Npads[8]   = {768,768,768,768,128,128,768,768};
        unsigned short* dsts[8] = {WhT, WtT, WfhT, WftT, WunetT, WmlpT, seqT, seqT+393216};
        for (int z = 0; z < 8; z++) {
            a.src[z]=srcs[z]; a.off[z]=offs[z]; a.K[z]=Ks[z];
            a.Ncols[z]=Ncols8[z]; a.Npad[z]=Npads[z]; a.dst[z]=dsts[z];
        }
        a.W_bil = W_bil; a.W_bilF = W_bilF;
        a.b_f = b_f; a.W_unet = W_unet; a.b_unet = b_unet;
        a.W_mlp = W_mlp; a.b_mlp = b_mlp; a.c23 = c23;
        a.W_rel = W_rel; a.WBt = WBt;
        a.seq = seq; a.attn = attn; a.entity_pos = entity_pos;
        a.mentb = mentb; a.ent_emb = ent_emb; a.ent_att = ent_att;
        prep_kernel<<<dim3(48, 16, 13), 256, 0, stream>>>(a, dtf);
    }
    // 2. ht attention (normalized, bf16)
    htatt_kernel<<<N_, 256, 0, stream>>>(ent_att, hts, htb);
    // 3. gemmA: rs (z=0,1) + T_{h,t} (z=2,3)
    {
        MfmaJob ga = {};
        ga.ent_emb = ent_emb; ga.rs = rs; ga.hts = hts;
        for (int z = 0; z < 2; z++) {
            ga.A[z] = htb + (long)z*256*512; ga.Bt[z] = seqT + (long)z*393216;
            ga.bias[z] = nullptr; ga.C[z] = rs + (long)z*256*768;
            ga.K[z] = 512; ga.ldc[z] = 768; ga.act[z] = 0; ga.obf[z] = 0;
            ga.asrc[z] = 0; ga.aside[z] = 0; ga.mx[z] = 4; ga.my[z] = 12;
        }
        ga.A[2] = mentb; ga.Bt[2] = WfhT; ga.bias[2] = nullptr; ga.C[2] = Tbh;
        ga.K[2] = 768; ga.ldc[2] = 768; ga.act[2] = 0; ga.obf[2] = 1;
        ga.asrc[2] = 0; ga.aside[2] = 0; ga.mx[2] = 4; ga.my[2] = 12;
        ga.A[3] = mentb; ga.Bt[3] = WftT; ga.bias[3] = nullptr; ga.C[3] = Tbt;
        ga.K[3] = 768; ga.ldc[3] = 768; ga.act[3] = 0; ga.obf[3] = 1;
        ga.asrc[3] = 0; ga.aside[3] = 0; ga.mx[3] = 4; ga.my[3] = 12;
        mfma_nt2_kernel<<<dim3(4, 12, 4), 256, 0, stream>>>(ga, dtf);
    }
    // 4. gemmBC: hz/tz (z=0,1; gather-cat A) + mu (z=2..5)
    {
        MfmaJob ga = {};
        ga.ent_emb = ent_emb; ga.rs = rs; ga.hts = hts;
        ga.A[0] = nullptr; ga.Bt[0] = WhT; ga.bias[0] = b_head; ga.C[0] = hz;
        ga.A[1] = nullptr; ga.Bt[1] = WtT; ga.bias[1] = b_tail; ga.C[1] = tz;
        for (int z = 0; z < 2; z++) {
            ga.K[z] = 1536; ga.ldc[z] = 768; ga.act[z] = 1; ga.obf[z] = 0;
            ga.asrc[z] = 1; ga.aside[z] = z; ga.mx[z] = 8; ga.my[z] = 12;
        }
        const unsigned short* As[4] = {Tbh, Tbt, Tbh, Tbt};
        const unsigned short* Bs[4] = {WunetT, WunetT, WmlpT, WmlpT};
        for (int q = 0; q < 4; q++) {
            int z = 2 + q;
            ga.A[z] = As[q]; ga.Bt[z] = Bs[q]; ga.bias[z] = nullptr;
            ga.C[z] = mu + q*32768;
            ga.K[z] = 768; ga.ldc[z] = 128; ga.act[z] = 0; ga.obf[z] = 0;
            ga.asrc[z] = 0; ga.aside[z] = 0; ga.mx[z] = 4; ga.my[z] = 2;
        }
        mfma_nt2_kernel<<<dim3(8, 12, 6), 256, 0, stream>>>(ga, dtf);
    }
    // 5. r1 partials (LDS dbuf, kz-fastest grid, bf16 partial)
    r1_mfma_kernel<<<dim3(KSPLIT_, 8), 256, 0, stream>>>(hz, tz, WBt, partial);
    // 6. fused reduce + r2/r3 + final projection
    r23out_kernel<<<N_, 128, 0, stream>>>(partial, b_rel, mu, c23, hts, mention_idx,
                                          W_bilF, b_bil, d_out, dtf);
}